// Round 4
// baseline (255.198 us; speedup 1.0000x reference)
//
#include <hip/hip_runtime.h>

// Problem constants
#define BB 8
#define LL 1024
#define KNB 30
#define NUM_RBF 16
#define NPOS 16
#define MAXREL 32
#define EDGE_C 128
#define EDGE_IN 416   // NPOS + 25*NUM_RBF
#define NKK 26        // 416 / 16 K-steps for 32x32x16 MFMA
#define NKH 13        // K-steps per half (K-split for LDS occupancy)
#define WTF_N (NKK * 4 * 64 * 8)   // 53248 fp16 elements

__constant__ int PAIR_I_d[25] = {0,1,2,3,4,0,0,0,0,1,1,1,4,4,3,1,2,3,4,2,3,4,2,3,2};
__constant__ int PAIR_J_d[25] = {0,1,2,3,4,1,2,3,4,2,3,4,2,3,2,0,0,0,0,1,1,1,4,4,3};

typedef _Float16 half8 __attribute__((ext_vector_type(8)));
typedef float floatx16 __attribute__((ext_vector_type(16)));

// -------- Kernel 1: kNN (4 rows per 256-thread block; one wave per row) --------
// Blocks >= 2048 instead repack W_edge into fragment-linear fp16 (folded wprep).
// UNCHANGED: exact f64 sortable keys + IEEE sqrtf (index output must match ref
// ordering bit-exactly; approx sqrt could reorder near-ties).
__global__ __launch_bounds__(256) void knn_kernel(const float* __restrict__ X,
                                                  const float* __restrict__ mask,
                                                  float* __restrict__ out_idx,
                                                  const float* __restrict__ W_edge,
                                                  _Float16* __restrict__ WtF) {
    if (blockIdx.x >= 2048) {
        // WtF[((kk*4+w)*64+l)*8+j] = W_edge[(kk*16+(l>>5)*8+j)*128 + w*32+(l&31)]
        int o = (blockIdx.x - 2048) * 256 + threadIdx.x;
        if (o < WTF_N) {
            int j = o & 7, l = (o >> 3) & 63, w = (o >> 9) & 3, kk = o >> 11;
            int k = (kk << 4) + ((l >> 5) << 3) + j;
            int n = (w << 5) + (l & 31);
            WtF[o] = (_Float16)W_edge[k * EDGE_C + n];
        }
        return;
    }

    int b = blockIdx.x >> 8;
    int i0 = (blockIdx.x & 255) * 4;
    int tid = threadIdx.x;
    int lane = tid & 63;
    int wv = tid >> 6;

    __shared__ float sCa[LL * 3];
    __shared__ float sMask[LL];

    for (int j = tid; j < LL; j += 256) {
        int base = (b * LL + j) * 12 + 3;     // Ca
        sCa[j * 3 + 0] = X[base + 0];
        sCa[j * 3 + 1] = X[base + 1];
        sCa[j * 3 + 2] = X[base + 2];
        sMask[j] = mask[b * LL + j];
    }
    __syncthreads();

    int i = i0 + wv;
    int row = b * LL + i;
    float cax = sCa[i * 3 + 0], cay = sCa[i * 3 + 1], caz = sCa[i * 3 + 2];
    float mi = sMask[i];

    float Dv[16];
    float dmax = 0.0f;
#pragma unroll
    for (int c = 0; c < 16; ++c) {
        int j = lane + c * 64;
        float dx = cax - sCa[j * 3 + 0];
        float dy = cay - sCa[j * 3 + 1];
        float dz = caz - sCa[j * 3 + 2];
        float m2 = mi * sMask[j];
        float D = m2 * sqrtf(dx * dx + dy * dy + dz * dz + 1e-6f);
        Dv[c] = D;
        dmax = fmaxf(dmax, D);
    }
    for (int o = 32; o; o >>= 1) dmax = fmaxf(dmax, __shfl_down(dmax, o));
    dmax = __shfl(dmax, 0);

    // exact sortable key: Dadj_bits * 1024 + j  (< 2^41, exact in f64)
    double cand[16];
#pragma unroll
    for (int c = 0; c < 16; ++c) {
        int j = lane + c * 64;
        float m2 = mi * sMask[j];
        float Dadj = Dv[c] + (1.0f - m2) * dmax;
        unsigned int bits = __float_as_uint(Dadj);
        cand[c] = fma((double)bits, 1024.0, (double)j);
    }

    const double KILL = 9.0e15;
    float myj = 0.0f;
    for (int r = 0; r < KNB; ++r) {
        // lane-local min: balanced fmin tree (v_min_f64)
        double a0 = fmin(cand[0], cand[1]);
        double a1 = fmin(cand[2], cand[3]);
        double a2 = fmin(cand[4], cand[5]);
        double a3 = fmin(cand[6], cand[7]);
        double a4 = fmin(cand[8], cand[9]);
        double a5 = fmin(cand[10], cand[11]);
        double a6 = fmin(cand[12], cand[13]);
        double a7 = fmin(cand[14], cand[15]);
        a0 = fmin(a0, a1); a2 = fmin(a2, a3); a4 = fmin(a4, a5); a6 = fmin(a6, a7);
        a0 = fmin(a0, a2); a4 = fmin(a4, a6);
        double m = fmin(a0, a4);
        // wave min
        for (int o = 32; o; o >>= 1) {
            double other = __shfl_down(m, o);
            m = fmin(m, other);
        }
        m = __shfl(m, 0);
        unsigned long long ku = (unsigned long long)m;   // exact
        int jw = __builtin_amdgcn_readfirstlane((int)(ku & 1023));
        bool own = (lane == (jw & 63));
        switch (jw >> 6) {   // scalar 16-way branch; one masked v_mov pair
            case 0:  if (own) cand[0]  = KILL; break;
            case 1:  if (own) cand[1]  = KILL; break;
            case 2:  if (own) cand[2]  = KILL; break;
            case 3:  if (own) cand[3]  = KILL; break;
            case 4:  if (own) cand[4]  = KILL; break;
            case 5:  if (own) cand[5]  = KILL; break;
            case 6:  if (own) cand[6]  = KILL; break;
            case 7:  if (own) cand[7]  = KILL; break;
            case 8:  if (own) cand[8]  = KILL; break;
            case 9:  if (own) cand[9]  = KILL; break;
            case 10: if (own) cand[10] = KILL; break;
            case 11: if (own) cand[11] = KILL; break;
            case 12: if (own) cand[12] = KILL; break;
            case 13: if (own) cand[13] = KILL; break;
            case 14: if (own) cand[14] = KILL; break;
            case 15: if (own) cand[15] = KILL; break;
        }
        if (lane == r) myj = (float)jw;
    }
    if (lane < KNB) out_idx[(size_t)row * KNB + lane] = myj;
}

// -------- Kernel 2: features -> MFMA f16 GEMM -> LayerNorm, one block per (b,i) --------
// v3: K-split into two 13-step halves reusing one 13.3KB fA buffer -> LDS 16384B
// -> 8 blocks/CU (wave-capped) instead of 5 (was latency/occupancy-bound:
// VALU 44.6 / Mfma 15.3 / HBM 21% / occ 43.8). B operand preloaded to VGPRs so
// L2 latency hides under the feature-build phases.
__global__ __launch_bounds__(256) void edge_kernel(const float* __restrict__ X,
                                                   const int* __restrict__ ridx,
                                                   const float* __restrict__ W_pos,
                                                   const float* __restrict__ b_pos,
                                                   const _Float16* __restrict__ WtF,
                                                   const float* __restrict__ gamma,
                                                   const float* __restrict__ beta,
                                                   const float* __restrict__ out_idx,
                                                   float* __restrict__ out_E) {
    int row = blockIdx.x;   // b*L + i
    int b = row >> 10;
    int i = row & 1023;
    int tid = threadIdx.x;

    // LDS overlay (16384 B total):
    //  [0, 13312)      fA  (13 k-steps of A-fragments fp16, reused per half)
    //                  / atoms (31*15 f32 = 1860 B, dead before build half0)
    //  [13312, 16320)  dist (30*25 f32)
    //  [0, 16384)      Esh (32x128 f32) after MFMA (fA + dist both dead)
    __shared__ __align__(16) char smem[16384];
    _Float16* fA = (_Float16*)smem;
    float* Esh = (float*)smem;
    float* atoms = (float*)smem;
    float* dist = (float*)(smem + 13312);

    int wv = tid >> 6;
    int l = tid & 63;

    // B preload, half 0: issue at kernel entry; latency hides under steps 1-2.
    const half8* Bp = (const half8*)WtF + wv * 64 + l;   // + kk*256
    half8 breg[NKH];
#pragma unroll
    for (int kk = 0; kk < NKH; ++kk) breg[kk] = Bp[kk * 256];

    // step 1: atoms for residue i and its 30 neighbors (out_idx is L2-hot).
    if (tid < 31) {
        int r = (tid == 0) ? i : (int)out_idx[(size_t)row * KNB + (tid - 1)];
        int base = (b * LL + r) * 12;
        float Nx = X[base + 0], Ny = X[base + 1], Nz = X[base + 2];
        float Cax = X[base + 3], Cay = X[base + 4], Caz = X[base + 5];
        float Cx = X[base + 6], Cy = X[base + 7], Cz = X[base + 8];
        float Ox = X[base + 9], Oy = X[base + 10], Oz = X[base + 11];
        float bx = Cax - Nx, by = Cay - Ny, bz = Caz - Nz;
        float cx = Cx - Cax, cy = Cy - Cay, cz = Cz - Caz;
        float ax = by * cz - bz * cy;
        float ay = bz * cx - bx * cz;
        float az = bx * cy - by * cx;
        float Cbx = -0.58273431f * ax + 0.56802827f * bx - 0.54067466f * cx + Cax;
        float Cby = -0.58273431f * ay + 0.56802827f * by - 0.54067466f * cy + Cay;
        float Cbz = -0.58273431f * az + 0.56802827f * bz - 0.54067466f * cz + Caz;
        float* A = &atoms[tid * 15];
        A[0] = Cax; A[1] = Cay; A[2] = Caz;
        A[3] = Nx;  A[4] = Ny;  A[5] = Nz;
        A[6] = Cx;  A[7] = Cy;  A[8] = Cz;
        A[9] = Ox;  A[10] = Oy; A[11] = Oz;
        A[12] = Cbx; A[13] = Cby; A[14] = Cbz;
    }
    __syncthreads();

    // step 2: 30*25 atom-pair distances (v_sqrt fine: feeds tolerance-checked RBF)
    for (int idx = tid; idx < KNB * 25; idx += 256) {
        int k = idx / 25;
        int p = idx - k * 25;
        const float* Ai = &atoms[PAIR_I_d[p] * 3];
        const float* Aj = &atoms[(1 + k) * 15 + PAIR_J_d[p] * 3];
        float dx = Ai[0] - Aj[0], dy = Ai[1] - Aj[1], dz = Ai[2] - Aj[2];
        dist[idx] = __builtin_amdgcn_sqrtf(dx * dx + dy * dy + dz * dz + 1e-6f);
    }
    __syncthreads();

    int m = tid & 31;
    int kgb = tid >> 5;          // 0..7; kg parity == kgb parity (26 is even)
    float cbase = (kgb & 1) ? 14.4f : 5.8666668f;   // 1.6 + 4h (+ 8h for odd chunks)
    const float SQL2E = 1.2011224f;   // sqrt(log2 e)
    const float C1 = 3.0777494f;      // 2h * log2 e
    const float C0 = 1.6414664f;      // h^2 * log2 e
    const float DK = 0.1027397f;      // exp(-2 h^2)

    floatx16 acc;
#pragma unroll
    for (int r = 0; r < 16; ++r) acc[r] = 0.0f;
    const half8* Ap = (const half8*)fA + l;              // + kkl*64

#pragma unroll
    for (int h = 0; h < 2; ++h) {
        // build half h: chunks kg = kgl + 26h, kgl in [0,26).
        // element (m,k): fA[((kgl>>1)*64 + m + 32*(kgl&1))*8 + (k&7)]
        // RBF via exact telescoping recurrence anchored at chunk CENTER (jj=4):
        //   f_4 = exp(2h*xc - h^2), b_4 = exp(-2h*xc - h^2), both decay by DK.
        // xc clamped to <=12 (NaN guard: fw=exp2(C1*xc-C0) overflows past xc~42
        // while r4 flushed to 0 -> 0*inf; chunks with xc>7.3 are exactly 0 in f16
        // either way, so the clamp is semantics-preserving).
#pragma unroll
        for (int r = 0; r < 4; ++r) {
            int kgl = kgb + 8 * r;
            if (kgl < 26) {
                int kg = kgl + 26 * h;
                half8 v8;
                if (m >= KNB) {
#pragma unroll
                    for (int jj = 0; jj < 8; ++jj) v8[jj] = (_Float16)0.0f;
                } else if (kg < 2) {
                    // positional features (half 0 only; folds away for h=1)
                    int jn = (int)out_idx[(size_t)row * KNB + m];
                    int off = ridx[row] - ridx[b * LL + jn] + MAXREL;
                    off = off < 0 ? 0 : (off > 2 * MAXREL ? 2 * MAXREL : off);
                    const float4* wp = (const float4*)&W_pos[off * NPOS + kg * 8];
                    const float4* bp = (const float4*)&b_pos[kg * 8];
                    float4 w0 = wp[0], w1 = wp[1];
                    float4 p0 = bp[0], p1 = bp[1];
                    v8[0] = (_Float16)(w0.x + p0.x);
                    v8[1] = (_Float16)(w0.y + p0.y);
                    v8[2] = (_Float16)(w0.z + p0.z);
                    v8[3] = (_Float16)(w0.w + p0.w);
                    v8[4] = (_Float16)(w1.x + p1.x);
                    v8[5] = (_Float16)(w1.y + p1.y);
                    v8[6] = (_Float16)(w1.z + p1.z);
                    v8[7] = (_Float16)(w1.w + p1.w);
                } else {
                    int p = (kg - 2) >> 1;               // atom-pair index
                    float d = dist[m * 25 + p];
                    float xc = fminf(fmaf(0.8f, d, -cbase), 12.0f);   // x at jj=4
                    float xs = xc * SQL2E;
                    float r4 = __builtin_amdgcn_exp2f(-xs * xs);
                    float fw = __builtin_amdgcn_exp2f(fmaf(C1, xc, -C0));
                    float bw = __builtin_amdgcn_exp2f(fmaf(-C1, xc, -C0));
                    float r5 = r4 * fw; fw *= DK;
                    float r6 = r5 * fw; fw *= DK;
                    float r7 = r6 * fw;
                    float r3 = r4 * bw; bw *= DK;
                    float r2 = r3 * bw; bw *= DK;
                    float r1 = r2 * bw; bw *= DK;
                    float r0 = r1 * bw;
                    v8[0] = (_Float16)r0; v8[1] = (_Float16)r1;
                    v8[2] = (_Float16)r2; v8[3] = (_Float16)r3;
                    v8[4] = (_Float16)r4; v8[5] = (_Float16)r5;
                    v8[6] = (_Float16)r6; v8[7] = (_Float16)r7;
                }
                int pos = ((kgl >> 1) * 64 + m + 32 * (kgl & 1)) * 8;
                *(half8*)(fA + pos) = v8;
            }
        }
        __syncthreads();   // fA(h) ready

        // MFMA over this half: wave wv computes 32 rows x cols [32wv, 32wv+32)
#pragma unroll
        for (int kk = 0; kk < NKH; ++kk) {
            half8 a = Ap[kk * 64];
            acc = __builtin_amdgcn_mfma_f32_32x32x16_f16(a, breg[kk], acc, 0, 0, 0);
        }
        if (h == 0) {
            // B preload, half 1: issues here, latency hides under build half 1.
#pragma unroll
            for (int kk = 0; kk < NKH; ++kk) breg[kk] = Bp[(NKH + kk) * 256];
        }
        __syncthreads();   // all waves done reading fA before overwrite / Esh
    }

    // step 5: spill C to LDS (C layout: col=l&31, row=(r&3)+8*(r>>2)+4*(l>>5))
#pragma unroll
    for (int r = 0; r < 16; ++r) {
        int rr = (r & 3) + 8 * (r >> 2) + 4 * (l >> 5);
        Esh[rr * EDGE_C + wv * 32 + (l & 31)] = acc[r];
    }
    __syncthreads();

    // step 6: LayerNorm, one pass: sum + sumsq with interleaved butterflies,
    // var = E[x^2] - mean^2, v_rsq instead of IEEE 1/sqrt.
    int cg = tid & 31;
    int ky = tid >> 5;
    int c0 = cg * 4;
    float gam0 = gamma[c0 + 0], gam1 = gamma[c0 + 1];
    float gam2 = gamma[c0 + 2], gam3 = gamma[c0 + 3];
    float bet0 = beta[c0 + 0], bet1 = beta[c0 + 1];
    float bet2 = beta[c0 + 2], bet3 = beta[c0 + 3];

#pragma unroll
    for (int r2 = 0; r2 < 4; ++r2) {
        int e = ky + 8 * r2;
        float4 v = *(const float4*)&Esh[e * EDGE_C + c0];
        float s = (v.x + v.y) + (v.z + v.w);
        float q = fmaf(v.x, v.x, fmaf(v.y, v.y, fmaf(v.z, v.z, v.w * v.w)));
#pragma unroll
        for (int o = 16; o; o >>= 1) {
            s += __shfl_xor(s, o);    // two independent chains -> latency-hidden
            q += __shfl_xor(q, o);
        }
        float mean = s * 0.0078125f;
        float var = fmaf(-mean, mean, q * 0.0078125f);
        float inv = __builtin_amdgcn_rsqf(var + 1e-5f);
        if (e < KNB) {
            float ig0 = inv * gam0, ig1 = inv * gam1;
            float ig2 = inv * gam2, ig3 = inv * gam3;
            float4 o4;
            o4.x = fmaf(v.x, ig0, fmaf(-mean, ig0, bet0));
            o4.y = fmaf(v.y, ig1, fmaf(-mean, ig1, bet1));
            o4.z = fmaf(v.z, ig2, fmaf(-mean, ig2, bet2));
            o4.w = fmaf(v.w, ig3, fmaf(-mean, ig3, bet3));
            *(float4*)(out_E + ((size_t)(row * KNB + e)) * EDGE_C + c0) = o4;
        }
    }
}

extern "C" void kernel_launch(void* const* d_in, const int* in_sizes, int n_in,
                              void* d_out, int out_size, void* d_ws, size_t ws_size,
                              hipStream_t stream) {
    const float* X      = (const float*)d_in[0];
    const float* mask   = (const float*)d_in[1];
    const int*   ridx   = (const int*)d_in[2];
    const float* W_pos  = (const float*)d_in[6];
    const float* b_pos  = (const float*)d_in[7];
    const float* W_edge = (const float*)d_in[8];
    const float* gamma  = (const float*)d_in[9];
    const float* beta   = (const float*)d_in[10];

    float* out_E   = (float*)d_out;
    float* out_idx = out_E + (size_t)BB * LL * KNB * EDGE_C;   // E_idx stored as floats
    _Float16* WtF  = (_Float16*)d_ws;                          // 106 KB fragment-linear W

    int knn_grid = 2048 + (WTF_N + 255) / 256;   // kNN blocks + folded W-prep blocks
    knn_kernel<<<knn_grid, 256, 0, stream>>>(X, mask, out_idx, W_edge, WtF);
    edge_kernel<<<BB * LL, 256, 0, stream>>>(X, ridx, W_pos, b_pos, WtF,
                                             gamma, beta, out_idx, out_E);
}

// Round 5
// 236.878 us; speedup vs baseline: 1.0773x; 1.0773x over previous
//
#include <hip/hip_runtime.h>

// Problem constants
#define BB 8
#define LL 1024
#define KNB 30
#define NUM_RBF 16
#define NPOS 16
#define MAXREL 32
#define EDGE_C 128
#define EDGE_IN 416   // NPOS + 25*NUM_RBF
#define NKK 26        // 416 / 16 K-steps for 32x32x16 MFMA
#define WTF_N (NKK * 4 * 64 * 8)   // 53248 fp8 BYTES (fragment-linear W)

__constant__ int PAIR_I_d[25] = {0,1,2,3,4,0,0,0,0,1,1,1,4,4,3,1,2,3,4,2,3,4,2,3,2};
__constant__ int PAIR_J_d[25] = {0,1,2,3,4,1,2,3,4,2,3,4,2,3,2,0,0,0,0,1,1,1,4,4,3};

typedef float floatx16 __attribute__((ext_vector_type(16)));

// -------- Kernel 1: kNN (4 rows per 256-thread block; one wave per row) --------
// Blocks >= 2048 instead repack W_edge into fragment-linear FP8 (folded wprep).
// UNCHANGED selection path: exact f64 sortable keys + IEEE sqrtf (index output
// must match ref ordering bit-exactly; approx sqrt could reorder near-ties).
__global__ __launch_bounds__(256) void knn_kernel(const float* __restrict__ X,
                                                  const float* __restrict__ mask,
                                                  float* __restrict__ out_idx,
                                                  const float* __restrict__ W_edge,
                                                  unsigned char* __restrict__ WtF) {
    if (blockIdx.x >= 2048) {
        // WtF[((kk*4+w)*64+l)*8+j] = fp8(W_edge[(kk*16+(l>>5)*8+j)*128 + w*32+(l&31)])
        int o = (blockIdx.x - 2048) * 256 + threadIdx.x;
        if (o < WTF_N) {
            int j = o & 7, l = (o >> 3) & 63, w = (o >> 9) & 3, kk = o >> 11;
            int k = (kk << 4) + ((l >> 5) << 3) + j;
            int n = (w << 5) + (l & 31);
            float wv = W_edge[k * EDGE_C + n];
            int pk = __builtin_amdgcn_cvt_pk_fp8_f32(wv, wv, 0, false);
            WtF[o] = (unsigned char)(pk & 0xFF);
        }
        return;
    }

    int b = blockIdx.x >> 8;
    int i0 = (blockIdx.x & 255) * 4;
    int tid = threadIdx.x;
    int lane = tid & 63;
    int wv = tid >> 6;

    __shared__ float sCa[LL * 3];
    __shared__ float sMask[LL];

    for (int j = tid; j < LL; j += 256) {
        int base = (b * LL + j) * 12 + 3;     // Ca
        sCa[j * 3 + 0] = X[base + 0];
        sCa[j * 3 + 1] = X[base + 1];
        sCa[j * 3 + 2] = X[base + 2];
        sMask[j] = mask[b * LL + j];
    }
    __syncthreads();

    int i = i0 + wv;
    int row = b * LL + i;
    float cax = sCa[i * 3 + 0], cay = sCa[i * 3 + 1], caz = sCa[i * 3 + 2];
    float mi = sMask[i];

    float Dv[16];
    float dmax = 0.0f;
#pragma unroll
    for (int c = 0; c < 16; ++c) {
        int j = lane + c * 64;
        float dx = cax - sCa[j * 3 + 0];
        float dy = cay - sCa[j * 3 + 1];
        float dz = caz - sCa[j * 3 + 2];
        float m2 = mi * sMask[j];
        float D = m2 * sqrtf(dx * dx + dy * dy + dz * dz + 1e-6f);
        Dv[c] = D;
        dmax = fmaxf(dmax, D);
    }
    for (int o = 32; o; o >>= 1) dmax = fmaxf(dmax, __shfl_down(dmax, o));
    dmax = __shfl(dmax, 0);

    // exact sortable key: Dadj_bits * 1024 + j  (< 2^41, exact in f64)
    double cand[16];
#pragma unroll
    for (int c = 0; c < 16; ++c) {
        int j = lane + c * 64;
        float m2 = mi * sMask[j];
        float Dadj = Dv[c] + (1.0f - m2) * dmax;
        unsigned int bits = __float_as_uint(Dadj);
        cand[c] = fma((double)bits, 1024.0, (double)j);
    }

    const double KILL = 9.0e15;
    float myj = 0.0f;
    for (int r = 0; r < KNB; ++r) {
        // lane-local min: balanced fmin tree (v_min_f64)
        double a0 = fmin(cand[0], cand[1]);
        double a1 = fmin(cand[2], cand[3]);
        double a2 = fmin(cand[4], cand[5]);
        double a3 = fmin(cand[6], cand[7]);
        double a4 = fmin(cand[8], cand[9]);
        double a5 = fmin(cand[10], cand[11]);
        double a6 = fmin(cand[12], cand[13]);
        double a7 = fmin(cand[14], cand[15]);
        a0 = fmin(a0, a1); a2 = fmin(a2, a3); a4 = fmin(a4, a5); a6 = fmin(a6, a7);
        a0 = fmin(a0, a2); a4 = fmin(a4, a6);
        double m = fmin(a0, a4);
        // wave min
        for (int o = 32; o; o >>= 1) {
            double other = __shfl_down(m, o);
            m = fmin(m, other);
        }
        m = __shfl(m, 0);
        unsigned long long ku = (unsigned long long)m;   // exact
        int jw = __builtin_amdgcn_readfirstlane((int)(ku & 1023));
        bool own = (lane == (jw & 63));
        switch (jw >> 6) {   // scalar 16-way branch; one masked v_mov pair
            case 0:  if (own) cand[0]  = KILL; break;
            case 1:  if (own) cand[1]  = KILL; break;
            case 2:  if (own) cand[2]  = KILL; break;
            case 3:  if (own) cand[3]  = KILL; break;
            case 4:  if (own) cand[4]  = KILL; break;
            case 5:  if (own) cand[5]  = KILL; break;
            case 6:  if (own) cand[6]  = KILL; break;
            case 7:  if (own) cand[7]  = KILL; break;
            case 8:  if (own) cand[8]  = KILL; break;
            case 9:  if (own) cand[9]  = KILL; break;
            case 10: if (own) cand[10] = KILL; break;
            case 11: if (own) cand[11] = KILL; break;
            case 12: if (own) cand[12] = KILL; break;
            case 13: if (own) cand[13] = KILL; break;
            case 14: if (own) cand[14] = KILL; break;
            case 15: if (own) cand[15] = KILL; break;
        }
        if (lane == r) myj = (float)jw;
    }
    if (lane < KNB) out_idx[(size_t)row * KNB + lane] = myj;
}

// -------- Kernel 2: features -> FP8 MFMA GEMM -> LayerNorm, one block per (b,i) --------
// v5 = r3 phase structure (proven 76.4us; r4's K-split regressed) with FP8 e4m3
// operands: mfma_f32_32x32x16_fp8_fp8 runs at f16 rate with HALF the bytes:
// fA 26.6->13.3KB (LDS 16.4KB total, same barriers), ds_read_b64 A-frags,
// 8B/lane B loads, 4 cvt_pk_fp8 per chunk instead of 8 f16 cvts.
// absmax threshold is 20.48; fp8 quantization costs ~0.3-1 absmax -> 20x margin.
__global__ __launch_bounds__(256) void edge_kernel(const float* __restrict__ X,
                                                   const int* __restrict__ ridx,
                                                   const float* __restrict__ W_pos,
                                                   const float* __restrict__ b_pos,
                                                   const unsigned char* __restrict__ WtF,
                                                   const float* __restrict__ gamma,
                                                   const float* __restrict__ beta,
                                                   const float* __restrict__ out_idx,
                                                   float* __restrict__ out_E) {
    int row = blockIdx.x;   // b*L + i
    int b = row >> 10;
    int i = row & 1023;
    int tid = threadIdx.x;

    // LDS overlay (16384 B):
    //  [0, 13312)      fA (A-fragments fp8) / atoms (31*15 f32, dead pre-build)
    //  [13312, 16312)  dist (30*25 f32)
    //  [0, 16384)      Esh (32x128 f32) after MFMA (fA + dist both dead)
    __shared__ __align__(16) char smem[16384];
    unsigned char* fA = (unsigned char*)smem;
    float* Esh = (float*)smem;
    float* atoms = (float*)smem;
    float* dist = (float*)(smem + 13312);

    // step 1: atoms for residue i and its 30 neighbors (out_idx is L2-hot).
    if (tid < 31) {
        int r = (tid == 0) ? i : (int)out_idx[(size_t)row * KNB + (tid - 1)];
        int base = (b * LL + r) * 12;
        float Nx = X[base + 0], Ny = X[base + 1], Nz = X[base + 2];
        float Cax = X[base + 3], Cay = X[base + 4], Caz = X[base + 5];
        float Cx = X[base + 6], Cy = X[base + 7], Cz = X[base + 8];
        float Ox = X[base + 9], Oy = X[base + 10], Oz = X[base + 11];
        float bx = Cax - Nx, by = Cay - Ny, bz = Caz - Nz;
        float cx = Cx - Cax, cy = Cy - Cay, cz = Cz - Caz;
        float ax = by * cz - bz * cy;
        float ay = bz * cx - bx * cz;
        float az = bx * cy - by * cx;
        float Cbx = -0.58273431f * ax + 0.56802827f * bx - 0.54067466f * cx + Cax;
        float Cby = -0.58273431f * ay + 0.56802827f * by - 0.54067466f * cy + Cay;
        float Cbz = -0.58273431f * az + 0.56802827f * bz - 0.54067466f * cz + Caz;
        float* A = &atoms[tid * 15];
        A[0] = Cax; A[1] = Cay; A[2] = Caz;
        A[3] = Nx;  A[4] = Ny;  A[5] = Nz;
        A[6] = Cx;  A[7] = Cy;  A[8] = Cz;
        A[9] = Ox;  A[10] = Oy; A[11] = Oz;
        A[12] = Cbx; A[13] = Cby; A[14] = Cbz;
    }
    __syncthreads();

    // step 2: 30*25 atom-pair distances (v_sqrt fine: feeds tolerance-checked RBF)
    for (int idx = tid; idx < KNB * 25; idx += 256) {
        int k = idx / 25;
        int p = idx - k * 25;
        const float* Ai = &atoms[PAIR_I_d[p] * 3];
        const float* Aj = &atoms[(1 + k) * 15 + PAIR_J_d[p] * 3];
        float dx = Ai[0] - Aj[0], dy = Ai[1] - Aj[1], dz = Ai[2] - Aj[2];
        dist[idx] = __builtin_amdgcn_sqrtf(dx * dx + dy * dy + dz * dz + 1e-6f);
    }
    __syncthreads();

    // step 3: build A-fragments (fp8) in MFMA order.
    // element (m,k): fA[((k>>4)*64 + m + 32*((k>>3)&1))*8 + (k&7)]  (bytes)
    // RBF via exact telescoping recurrence anchored at chunk CENTER (jj=4):
    //   f_4 = exp(2h*xc - h^2), b_4 = exp(-2h*xc - h^2), both decay by DK.
    // xc clamped to <=12 (NaN guard: fw=exp2(C1*xc-C0) would overflow past xc~42
    // while r4 flushed to 0 -> 0*inf; chunks with xc>7.3 are exactly 0 in fp8
    // either way, so the clamp is semantics-preserving).
    {
        int m = tid & 31;
        int kgb = tid >> 5;          // 0..7; kg parity == kgb parity
        float cbase = (kgb & 1) ? 14.4f : 5.8666668f;   // 1.6 + 4h (+ 8h odd chunks)
        const float SQL2E = 1.2011224f;   // sqrt(log2 e)
        const float C1 = 3.0777494f;      // 2h * log2 e
        const float C0 = 1.6414664f;      // h^2 * log2 e
        const float DK = 0.1027397f;      // exp(-2 h^2)
#pragma unroll
        for (int r = 0; r < 7; ++r) {
            int kg = kgb + 8 * r;
            if (kg < 52) {
                int lo, hi;
                if (m >= KNB) {
                    lo = 0; hi = 0;
                } else if (kg < 2) {
                    // positional features; dclip computed inline (L2-hot)
                    int jn = (int)out_idx[(size_t)row * KNB + m];
                    int off = ridx[row] - ridx[b * LL + jn] + MAXREL;
                    off = off < 0 ? 0 : (off > 2 * MAXREL ? 2 * MAXREL : off);
                    const float4* wp = (const float4*)&W_pos[off * NPOS + kg * 8];
                    const float4* bp = (const float4*)&b_pos[kg * 8];
                    float4 w0 = wp[0], w1 = wp[1];
                    float4 p0 = bp[0], p1 = bp[1];
                    lo = __builtin_amdgcn_cvt_pk_fp8_f32(w0.x + p0.x, w0.y + p0.y, 0, false);
                    lo = __builtin_amdgcn_cvt_pk_fp8_f32(w0.z + p0.z, w0.w + p0.w, lo, true);
                    hi = __builtin_amdgcn_cvt_pk_fp8_f32(w1.x + p1.x, w1.y + p1.y, 0, false);
                    hi = __builtin_amdgcn_cvt_pk_fp8_f32(w1.z + p1.z, w1.w + p1.w, hi, true);
                } else {
                    int p = (kg - 2) >> 1;               // atom-pair index
                    float d = dist[m * 25 + p];
                    float xc = fminf(fmaf(0.8f, d, -cbase), 12.0f);   // x at jj=4
                    float xs = xc * SQL2E;
                    float r4 = __builtin_amdgcn_exp2f(-xs * xs);
                    float fw = __builtin_amdgcn_exp2f(fmaf(C1, xc, -C0));
                    float bw = __builtin_amdgcn_exp2f(fmaf(-C1, xc, -C0));
                    float r5 = r4 * fw; fw *= DK;
                    float r6 = r5 * fw; fw *= DK;
                    float r7 = r6 * fw;
                    float r3 = r4 * bw; bw *= DK;
                    float r2 = r3 * bw; bw *= DK;
                    float r1 = r2 * bw; bw *= DK;
                    float r0 = r1 * bw;
                    lo = __builtin_amdgcn_cvt_pk_fp8_f32(r0, r1, 0, false);
                    lo = __builtin_amdgcn_cvt_pk_fp8_f32(r2, r3, lo, true);
                    hi = __builtin_amdgcn_cvt_pk_fp8_f32(r4, r5, 0, false);
                    hi = __builtin_amdgcn_cvt_pk_fp8_f32(r6, r7, hi, true);
                }
                int pos = ((kg >> 1) * 64 + m + 32 * (kg & 1)) * 8;
                long v = ((long)(unsigned int)hi << 32) | (unsigned int)lo;
                *(long*)(fA + pos) = v;
            }
        }
    }
    __syncthreads();

    // step 4: FP8 MFMA K-loop. wave wv computes 32 rows x cols [32wv, 32wv+32)
    int wv = tid >> 6;
    int l = tid & 63;
    floatx16 acc;
#pragma unroll
    for (int r = 0; r < 16; ++r) acc[r] = 0.0f;

    const long* Ap = (const long*)fA + l;                       // + kk*64
    const long* Bp = (const long*)WtF + wv * 64 + l;            // + kk*256
#pragma unroll 4
    for (int kk = 0; kk < NKK; ++kk) {
        long a = Ap[kk * 64];
        long bfr = Bp[kk * 256];
        acc = __builtin_amdgcn_mfma_f32_32x32x16_fp8_fp8(a, bfr, acc, 0, 0, 0);
    }
    __syncthreads();   // everyone done reading fA before overlay write

    // step 5: spill C to LDS (C layout: col=l&31, row=(r&3)+8*(r>>2)+4*(l>>5))
#pragma unroll
    for (int r = 0; r < 16; ++r) {
        int rr = (r & 3) + 8 * (r >> 2) + 4 * (l >> 5);
        Esh[rr * EDGE_C + wv * 32 + (l & 31)] = acc[r];
    }
    __syncthreads();

    // step 6: LayerNorm, one pass: sum + sumsq with interleaved butterflies,
    // var = E[x^2] - mean^2, v_rsq instead of IEEE 1/sqrt.
    int cg = tid & 31;
    int ky = tid >> 5;
    int c0 = cg * 4;
    float gam0 = gamma[c0 + 0], gam1 = gamma[c0 + 1];
    float gam2 = gamma[c0 + 2], gam3 = gamma[c0 + 3];
    float bet0 = beta[c0 + 0], bet1 = beta[c0 + 1];
    float bet2 = beta[c0 + 2], bet3 = beta[c0 + 3];

#pragma unroll
    for (int r2 = 0; r2 < 4; ++r2) {
        int e = ky + 8 * r2;
        float4 v = *(const float4*)&Esh[e * EDGE_C + c0];
        float s = (v.x + v.y) + (v.z + v.w);
        float q = fmaf(v.x, v.x, fmaf(v.y, v.y, fmaf(v.z, v.z, v.w * v.w)));
#pragma unroll
        for (int o = 16; o; o >>= 1) {
            s += __shfl_xor(s, o);    // two independent chains -> latency-hidden
            q += __shfl_xor(q, o);
        }
        float mean = s * 0.0078125f;
        float var = fmaf(-mean, mean, q * 0.0078125f);
        float inv = __builtin_amdgcn_rsqf(var + 1e-5f);
        if (e < KNB) {
            float ig0 = inv * gam0, ig1 = inv * gam1;
            float ig2 = inv * gam2, ig3 = inv * gam3;
            float4 o4;
            o4.x = fmaf(v.x, ig0, fmaf(-mean, ig0, bet0));
            o4.y = fmaf(v.y, ig1, fmaf(-mean, ig1, bet1));
            o4.z = fmaf(v.z, ig2, fmaf(-mean, ig2, bet2));
            o4.w = fmaf(v.w, ig3, fmaf(-mean, ig3, bet3));
            *(float4*)(out_E + ((size_t)(row * KNB + e)) * EDGE_C + c0) = o4;
        }
    }
}

extern "C" void kernel_launch(void* const* d_in, const int* in_sizes, int n_in,
                              void* d_out, int out_size, void* d_ws, size_t ws_size,
                              hipStream_t stream) {
    const float* X      = (const float*)d_in[0];
    const float* mask   = (const float*)d_in[1];
    const int*   ridx   = (const int*)d_in[2];
    const float* W_pos  = (const float*)d_in[6];
    const float* b_pos  = (const float*)d_in[7];
    const float* W_edge = (const float*)d_in[8];
    const float* gamma  = (const float*)d_in[9];
    const float* beta   = (const float*)d_in[10];

    float* out_E   = (float*)d_out;
    float* out_idx = out_E + (size_t)BB * LL * KNB * EDGE_C;   // E_idx stored as floats
    unsigned char* WtF = (unsigned char*)d_ws;                 // 53 KB fragment-linear fp8 W

    int knn_grid = 2048 + (WTF_N + 255) / 256;   // kNN blocks + folded W-prep blocks
    knn_kernel<<<knn_grid, 256, 0, stream>>>(X, mask, out_idx, W_edge, WtF);
    edge_kernel<<<BB * LL, 256, 0, stream>>>(X, ridx, W_pos, b_pos, WtF,
                                             gamma, beta, out_idx, out_E);
}